// Round 8
// baseline (272.908 us; speedup 1.0000x reference)
//
#include <hip/hip_runtime.h>
#include <hip/hip_bf16.h>

// ChunkedCrossAttention (RETRO-style), MI355X gfx950.
// N=2048 M=64 K=2 R=512 D=1024 H=16 DH=64 LCH=32
//
// Round 8: gemm256 restructured to 2 phases per K-tile (k0-phase, k1-phase),
// 32 MFMA per phase, full 8-load next-tile stage in ph_k0, one vmcnt(0) at
// ph_k1 end (before closing barrier). Halves barrier/lgkm sync points per
// MFMA vs round 7 (1 block/CU means sync stalls are fully exposed).

using u16 = unsigned short;
using u32 = unsigned int;

typedef float  f32x4   __attribute__((ext_vector_type(4)));
typedef __bf16 bf16x8v __attribute__((ext_vector_type(8)));
typedef __bf16 bf16x4v __attribute__((ext_vector_type(4)));
typedef short  s16x4   __attribute__((ext_vector_type(4)));
typedef u16    u16x8   __attribute__((ext_vector_type(8)));
typedef u16    u16x4v  __attribute__((ext_vector_type(4)));

#define SCALE_LOG2E (1.4426950408889634f / 32.0f)

__device__ __forceinline__ u16 f2b(float f){ return __builtin_bit_cast(u16, (__bf16)f); }
// XOR swizzle on 16B slots within 128B LDS rows
__device__ __forceinline__ int swz(int row, int cb){ return row*128 + (cb ^ ((row & 7) << 4)); }

// async global->LDS, 16B per lane, wave-uniform LDS base (guide §5 / m97)
__device__ __forceinline__ void gl_lds16(const void* g, void* l) {
    __builtin_amdgcn_global_load_lds(
        (const __attribute__((address_space(1))) unsigned int*)(unsigned long long)g,
        (__attribute__((address_space(3))) unsigned int*)(unsigned int)(unsigned long long)l,
        16, 0, 0);
}

// ===========================================================================
// 256x256 GEMM (KV projection): C(MxN) = A(MxKc) @ B(NxKc)^T, bf16.
// OM=3 epilogue: bn<1024 -> Ka row-major (ld 1024); bn>=1024 -> Vt^T via LDS
// transpose, coalesced 16B stores.
// 512 threads = 8 waves (2M x 4N), per-wave 128x64 output, BK=64, NT=Kc/64.
// LDS 128KB: A dbuf[2] x half[2] x 16KB at [0,64K); B same at [64K,128K).
// Per tile t (2 phases):
//   ph_k0: 12 ds_reads (A mh0+mh1, B) @k0 | stage 8 loads of t+1 |
//          barrier; lgkm0; 32 MFMA; barrier
//   ph_k1: 12 ds_reads @k1 | barrier; lgkm0; 32 MFMA; vmcnt(0); barrier
// vmcnt(0) drains t+1's loads (issued ~1 tile earlier, slack >> HBM latency);
// the closing barrier publishes them across waves (round-5 discipline).
// ===========================================================================
template<int OM>
__global__ __launch_bounds__(512, 2)
void gemm256(const u16* __restrict__ Ap, int lda,
             const u16* __restrict__ Bp, int ldb,
             void* __restrict__ Cp, void* __restrict__ Cp2,
             int M, int Kc, int nNt)
{
    __shared__ char Ls[131072];
    char* const Abase = Ls;
    char* const Bbase = Ls + 65536;

    const int tid  = threadIdx.x;
    const int lane = tid & 63, wave = tid >> 6;
    const int li = lane & 15, lg = lane >> 4;
    const int wr = wave >> 2, wc = wave & 3;

    const int nwg  = gridDim.x;
    const int lin  = blockIdx.x;
    const int lin2 = (lin & 7) * (nwg >> 3) + (lin >> 3);   // XCD chunk swizzle
    const long bm = (long)(lin2 / nNt) * 256;
    const long bn = (long)(lin2 % nNt) * 256;

    // staging geometry: 512 threads x 16B = 8KB = 64 rows/issue; 2 issues/half-tile
    const int srow = tid >> 3;                         // 0..63
    const int scol = ((tid & 7) ^ (srow & 7)) << 3;    // pre-swizzled col (elems)

    auto stageA = [&](int t, int hh) {
        char* d = Abase + (t & 1)*32768 + hh*16384 + wave*1024;
        long r0 = bm + hh*128 + srow;      if (r0 >= M) r0 = M - 1;
        long r1 = bm + hh*128 + 64 + srow; if (r1 >= M) r1 = M - 1;
        gl_lds16(Ap + r0*(long)lda + (long)t*64 + scol, d);
        gl_lds16(Ap + r1*(long)lda + (long)t*64 + scol, d + 8192);
    };
    auto stageB = [&](int t, int hh) {
        char* d = Bbase + (t & 1)*32768 + hh*16384 + wave*1024;
        long r0 = bn + hh*128 + srow;
        gl_lds16(Bp + r0*(long)ldb + (long)t*64 + scol, d);
        gl_lds16(Bp + (r0 + 64)*(long)ldb + (long)t*64 + scol, d + 8192);
    };

    const int NT = Kc >> 6;

    // prologue: stage tile0 fully (8 loads), drain, publish
    stageA(0, 0); stageA(0, 1); stageB(0, 0); stageB(0, 1);
    asm volatile("s_waitcnt vmcnt(0)" ::: "memory");
    asm volatile("s_barrier" ::: "memory");

    // read-side per-thread constants
    const int swx = (li & 7) << 4;
    const int cb0 = (lg*16) ^ swx;          // k-step 0 column bytes (swizzled)
    const int cb1 = (64 + lg*16) ^ swx;     // k-step 1
    const int arb = li;                     // + mh*64 + mt*16, within wr half
    const int brb = (wc & 1)*64 + li;       // + nt*16, within wc>>1 half

    f32x4 acc[8][4] = {};
    bf16x8v a[8], b[4];

#define MFMA32()                                                                \
    __builtin_amdgcn_s_setprio(1);                                              \
    _Pragma("unroll") for (int mh = 0; mh < 2; mh++)                            \
        _Pragma("unroll") for (int mt = 0; mt < 4; mt++)                        \
            _Pragma("unroll") for (int nt = 0; nt < 4; nt++)                    \
                acc[mh*4 + mt][nt] = __builtin_amdgcn_mfma_f32_16x16x32_bf16(   \
                    a[mh*4 + mt], b[nt], acc[mh*4 + mt][nt], 0, 0, 0);          \
    __builtin_amdgcn_s_setprio(0);

#define BAR_IN()  asm volatile("s_barrier" ::: "memory");                       \
                  asm volatile("s_waitcnt lgkmcnt(0)" ::: "memory");            \
                  __builtin_amdgcn_sched_barrier(0);
#define BAR_OUT() asm volatile("s_barrier" ::: "memory");
#define RD_AB(CB)                                                               \
    _Pragma("unroll") for (int mt = 0; mt < 4; mt++) {                          \
        a[mt]     = *(const bf16x8v*)(At + (arb + mt*16)*128 + (CB));           \
        a[4 + mt] = *(const bf16x8v*)(At + (arb + 64 + mt*16)*128 + (CB));      \
    }                                                                           \
    _Pragma("unroll") for (int nt = 0; nt < 4; nt++)                            \
        b[nt] = *(const bf16x8v*)(Bt + (brb + nt*16)*128 + (CB));

    for (int t = 0; t < NT; ++t) {
        char* At = Abase + (t & 1)*32768 + wr*16384;
        char* Bt = Bbase + (t & 1)*32768 + (wc >> 1)*16384;

        // ---- ph_k0: reads @k0, stage full tile t+1
        RD_AB(cb0);
        if (t + 1 < NT) {
            stageA(t + 1, 0); stageA(t + 1, 1);
            stageB(t + 1, 0); stageB(t + 1, 1);
        }
        BAR_IN(); MFMA32(); BAR_OUT();
        // ---- ph_k1: reads @k1, drain next tile's loads at the end
        RD_AB(cb1);
        BAR_IN(); MFMA32();
        asm volatile("s_waitcnt vmcnt(0)" ::: "memory");
        BAR_OUT();
    }
#undef MFMA32
#undef BAR_IN
#undef BAR_OUT
#undef RD_AB

    if (OM == 3 && bn >= 1024) {
        // --- V-block epilogue: LDS transpose -> coalesced Vt stores ---
        // After final barrier all staged-LDS reads are drained; Ls is free.
        u16* Vt = (u16*)Cp2;
        #pragma unroll
        for (int ai = 0; ai < 8; ai++) {
            const int m0 = wr*128 + (ai >> 2)*64 + (ai & 3)*16 + lg*4;   // 4-aligned
            #pragma unroll
            for (int nt = 0; nt < 4; nt++) {
                const int n = wc*64 + nt*16 + li;
                f32x4 c = acc[ai][nt];
                bf16x4v w;
                #pragma unroll
                for (int j = 0; j < 4; j++) w[j] = (__bf16)c[j];
                // [n][m] tile, 512B rows; 16B-granule XOR swizzle by n
                *(bf16x4v*)(Ls + n*512 + ((m0*2) ^ ((n & 31) << 4))) = w;
            }
        }
        __syncthreads();
        const int n    = tid >> 1;              // Vt-local row 0..255
        const int half = (tid & 1) * 128;       // m half
        u16* dst = Vt + (bn - 1024 + n)*32768L + bm + half;
        #pragma unroll
        for (int i = 0; i < 16; i++) {
            const int mb = (half + i*8) * 2;    // byte offset, 16B aligned
            uint4 v = *(const uint4*)(Ls + n*512 + (mb ^ ((n & 31) << 4)));
            *(uint4*)(dst + i*8) = v;
        }
    } else if (OM == 3) {
        // --- K-block epilogue: row-major 2B stores (32B runs per row) ---
        u16* Ka = (u16*)Cp;
        #pragma unroll
        for (int ai = 0; ai < 8; ai++) {
            #pragma unroll
            for (int nt = 0; nt < 4; nt++) {
                f32x4 c = acc[ai][nt];
                const long row0 = bm + wr*128 + (ai >> 2)*64 + (ai & 3)*16 + lg*4;
                const long col  = bn + wc*64 + nt*16 + li;
                #pragma unroll
                for (int j = 0; j < 4; j++) {
                    long rg = row0 + j;
                    if (rg < M) Ka[rg*1024 + col] = f2b(c[j]);
                }
            }
        }
    }
}

// ---------------------------------------------------------------------------
// 128x128x64-step GEMM (Q/Wo projections + fallback), unchanged from round 3.
// ---------------------------------------------------------------------------
template<bool AF32, int OM>
__global__ __launch_bounds__(256)
void gemm128(const void* __restrict__ Ap, int lda,
             const u16* __restrict__ Bp, int ldb,
             void* __restrict__ Cp, void* __restrict__ Cp2,
             int M, int Kc, int row_off, int nNt)
{
    __shared__ char As[128*128];
    __shared__ char Bs[128*128];
    const int tid  = threadIdx.x;
    const int lane = tid & 63, wave = tid >> 6;
    const int li = lane & 15, lg = lane >> 4;
    const int wr = wave >> 1, wc = wave & 1;

    const int nwg  = gridDim.x;
    const int lin  = blockIdx.x;
    const int lin2 = (lin & 7) * (nwg >> 3) + (lin >> 3);
    const long bm = (long)(lin2 / nNt) * 128;
    const long bn = (long)(lin2 % nNt) * 128;

    const int grow = wave*32 + (lane >> 3);
    const int gcol = ((lane & 7) ^ (lane >> 3)) << 3;
    const int sr = tid >> 1, sc = (tid & 1) * 32;
    long arow_f = bm + sr; if (arow_f >= M) arow_f = M - 1;
    long arow_g[4];
    #pragma unroll
    for (int j = 0; j < 4; j++) {
        long r = bm + grow + j*8;
        arow_g[j] = (r < M) ? r : (M - 1);
    }

    f32x4 acc[4][4] = {};

    for (int k0 = 0; k0 < Kc; k0 += 64) {
        float4 a4[8];
        if (AF32) {
            const float4* ap = (const float4*)((const float*)Ap + arow_f*lda + k0 + sc);
            #pragma unroll
            for (int i = 0; i < 8; i++) a4[i] = ap[i];
        }
        __syncthreads();
        if (!AF32) {
            #pragma unroll
            for (int j = 0; j < 4; j++)
                gl_lds16((const u16*)Ap + arow_g[j]*(long)lda + k0 + gcol,
                         As + (wave*4 + j)*1024);
        }
        #pragma unroll
        for (int j = 0; j < 4; j++)
            gl_lds16(Bp + (bn + grow + j*8)*(long)ldb + k0 + gcol,
                     Bs + (wave*4 + j)*1024);
        if (AF32) {
            #pragma unroll
            for (int i = 0; i < 4; i++) {
                float4 f0 = a4[2*i], f1 = a4[2*i+1];
                bf16x8v w;
                w[0]=(__bf16)f0.x; w[1]=(__bf16)f0.y; w[2]=(__bf16)f0.z; w[3]=(__bf16)f0.w;
                w[4]=(__bf16)f1.x; w[5]=(__bf16)f1.y; w[6]=(__bf16)f1.z; w[7]=(__bf16)f1.w;
                *(bf16x8v*)(As + swz(sr, sc*2 + i*16)) = w;
            }
        }
        __syncthreads();
        #pragma unroll
        for (int es = 0; es < 2; es++) {
            bf16x8v af[4], bfv[4];
            #pragma unroll
            for (int mt = 0; mt < 4; mt++)
                af[mt] = *(const bf16x8v*)(As + swz(wr*64 + mt*16 + li, es*64 + lg*16));
            #pragma unroll
            for (int nt = 0; nt < 4; nt++)
                bfv[nt] = *(const bf16x8v*)(Bs + swz(wc*64 + nt*16 + li, es*64 + lg*16));
            #pragma unroll
            for (int mt = 0; mt < 4; mt++)
                #pragma unroll
                for (int nt = 0; nt < 4; nt++)
                    acc[mt][nt] = __builtin_amdgcn_mfma_f32_16x16x32_bf16(
                        af[mt], bfv[nt], acc[mt][nt], 0, 0, 0);
        }
    }

    #pragma unroll
    for (int mt = 0; mt < 4; mt++) {
        #pragma unroll
        for (int nt = 0; nt < 4; nt++) {
            f32x4 c = acc[mt][nt];
            const long row0 = bm + wr*64 + mt*16 + lg*4;
            const long col  = bn + wc*64 + nt*16 + li;
            if (OM == 0) {
                u16* C = (u16*)Cp;
                #pragma unroll
                for (int j = 0; j < 4; j++) {
                    long rg = row0 + j;
                    if (rg < M) C[rg*1024 + col] = f2b(c[j]);
                }
            } else if (OM == 2) {
                float* C = (float*)Cp;
                #pragma unroll
                for (int j = 0; j < 4; j++) {
                    long rg = row0 + j;
                    if (rg < M) C[(row_off + rg)*1024 + col] = c[j];
                }
            } else {
                if (col < 1024) {
                    u16* Ka = (u16*)Cp;
                    #pragma unroll
                    for (int j = 0; j < 4; j++) Ka[(row0 + j)*1024 + col] = f2b(c[j]);
                } else {
                    u16* Vt = (u16*)Cp2;
                    bf16x4v w;
                    #pragma unroll
                    for (int j = 0; j < 4; j++) w[j] = (__bf16)c[j];
                    *(bf16x4v*)(Vt + (col - 1024)*32768L + row0) = w;
                }
            }
        }
    }
}

// ---------------------------------------------------------------------------
// Attention: grid (31, 16) = (chunk u, head h), 4 waves stride 64 substeps.
// ---------------------------------------------------------------------------
__global__ __launch_bounds__(256)
void attn_kernel(const u16* __restrict__ Qa, const u16* __restrict__ Ka,
                 const u16* __restrict__ Vt, u16* __restrict__ Om)
{
    const int u = blockIdx.x, h = blockIdx.y;
    const int tid = threadIdx.x;
    const int lane = tid & 63, wave = tid >> 6;
    const int li = lane & 15, lg = lane >> 4;

    bf16x8v qf[4][2];
    #pragma unroll
    for (int qt = 0; qt < 4; qt++)
        #pragma unroll
        for (int es = 0; es < 2; es++)
            qf[qt][es] = *(const bf16x8v*)(Qa + (long)(63 + u*64 + qt*16 + li)*1024
                                              + h*64 + es*32 + lg*8);

    f32x4 acc[4][4] = {};

    for (int it = wave; it < 64; it += 4) {
        const int k = it >> 5, rsub = it & 31;
        const long kr = (long)u*1024 + k*512 + rsub*16;

        bf16x8v a0 = *(const bf16x8v*)(Ka + (kr + li)*1024 + h*64 + lg*8);
        bf16x8v a1 = *(const bf16x8v*)(Ka + (kr + li)*1024 + h*64 + 32 + lg*8);
        f32x4 s[4];
        #pragma unroll
        for (int qt = 0; qt < 4; qt++) {
            f32x4 c = {};
            c = __builtin_amdgcn_mfma_f32_16x16x32_bf16(a0, qf[qt][0], c, 0, 0, 0);
            c = __builtin_amdgcn_mfma_f32_16x16x32_bf16(a1, qf[qt][1], c, 0, 0, 0);
            s[qt] = c;
        }
        float p[4][4];
        #pragma unroll
        for (int qt = 0; qt < 4; qt++)
            #pragma unroll
            for (int j = 0; j < 4; j++)
                p[qt][j] = __builtin_amdgcn_exp2f(s[qt][j]);
        float rz[4];
        #pragma unroll
        for (int j = 0; j < 4; j++) {
            float z = p[0][j] + p[1][j] + p[2][j] + p[3][j];
            z += __shfl_xor(z, 1); z += __shfl_xor(z, 2);
            z += __shfl_xor(z, 4); z += __shfl_xor(z, 8);
            rz[j] = __builtin_amdgcn_rcpf(z);
        }
        s16x4 wf[4];
        #pragma unroll
        for (int qt = 0; qt < 4; qt++) {
            bf16x4v w;
            #pragma unroll
            for (int j = 0; j < 4; j++) w[j] = (__bf16)(p[qt][j] * rz[j]);
            wf[qt] = __builtin_bit_cast(s16x4, w);
        }
        #pragma unroll
        for (int et = 0; et < 4; et++) {
            s16x4 va = *(const s16x4*)(Vt + (long)(h*64 + et*16 + li)*32768 + kr + lg*4);
            #pragma unroll
            for (int qt = 0; qt < 4; qt++)
                acc[et][qt] = __builtin_amdgcn_mfma_f32_16x16x16bf16_1k(
                    va, wf[qt], acc[et][qt], 0, 0, 0);
        }
    }

    __shared__ float Osum[64*64];
    for (int w = 0; w < 4; w++) {
        if (wave == w) {
            #pragma unroll
            for (int et = 0; et < 4; et++)
                #pragma unroll
                for (int qt = 0; qt < 4; qt++)
                    #pragma unroll
                    for (int j = 0; j < 4; j++) {
                        int e = et*16 + lg*4 + j, q = qt*16 + li;
                        if (w == 0) Osum[e*64 + q]  = acc[et][qt][j];
                        else        Osum[e*64 + q] += acc[et][qt][j];
                    }
        }
        __syncthreads();
    }
    const int q = tid & 63, e0 = (tid >> 6) * 16;
    u16x8 o0, o1;
    #pragma unroll
    for (int i = 0; i < 8; i++) {
        o0[i] = f2b(0.5f * Osum[(e0 + i    )*64 + q]);
        o1[i] = f2b(0.5f * Osum[(e0 + 8 + i)*64 + q]);
    }
    u16* dst = Om + (long)(u*64 + q)*1024 + h*64 + e0;
    *(u16x8*)dst       = o0;
    *(u16x8*)(dst + 8) = o1;
}

// ---------------------------------------------------------------------------
__global__ __launch_bounds__(256)
void convert_w(const float* __restrict__ Wq, const float* __restrict__ Wk,
               const float* __restrict__ Wv, const float* __restrict__ Wo,
               u16* __restrict__ dst)
{
    int idx = blockIdx.x*256 + threadIdx.x;
    int w   = idx >> 18;
    int off = (idx & 262143) << 2;
    const float* src = (w == 0) ? Wq : (w == 1) ? Wk : (w == 2) ? Wv : Wo;
    float scv = (w == 0) ? SCALE_LOG2E : 1.0f;
    float4 v = *(const float4*)(src + off);
    u16x4v o = { f2b(v.x*scv), f2b(v.y*scv), f2b(v.z*scv), f2b(v.w*scv) };
    *(u16x4v*)(dst + (long)w*1048576 + off) = o;
}

__global__ __launch_bounds__(256)
void convert_a(const float* __restrict__ src, u16* __restrict__ dst, int n8)
{
    int i = blockIdx.x*256 + threadIdx.x;
    const int stride = gridDim.x*256;
    for (; i < n8; i += stride) {
        float4 f0 = ((const float4*)src)[2*i], f1 = ((const float4*)src)[2*i+1];
        u16x8 o = { f2b(f0.x), f2b(f0.y), f2b(f0.z), f2b(f0.w),
                    f2b(f1.x), f2b(f1.y), f2b(f1.z), f2b(f1.w) };
        ((u16x8*)dst)[i] = o;
    }
}

__global__ __launch_bounds__(256)
void last_kernel(const u16* __restrict__ Vt, u16* __restrict__ Om)
{
    const int row  = blockIdx.x*4 + (threadIdx.x >> 6);
    const int lane = threadIdx.x & 63;
    const u16* p = Vt + (long)row*32768 + 31*1024 + lane*16;
    float s = 0.f;
    #pragma unroll
    for (int hf = 0; hf < 2; hf++) {
        bf16x8v v = *(const bf16x8v*)(p + hf*8);
        #pragma unroll
        for (int i = 0; i < 8; i++) s += (float)v[i];
    }
    #pragma unroll
    for (int m = 1; m < 64; m <<= 1) s += __shfl_xor(s, m);
    if (lane == 0) Om[(long)1984*1024 + row] = f2b(0.5f * s);
}

__global__ __launch_bounds__(256)
void copy_head(const float* __restrict__ x, float* __restrict__ out)
{
    int i = blockIdx.x*256 + threadIdx.x;
    ((float4*)out)[i] = ((const float4*)x)[i];
}

// ---------------------------------------------------------------------------
extern "C" void kernel_launch(void* const* d_in, const int* in_sizes, int n_in,
                              void* d_out, int out_size, void* d_ws, size_t ws_size,
                              hipStream_t stream)
{
    const float* x  = (const float*)d_in[0];
    const float* nb = (const float*)d_in[1];
    const float* Wq = (const float*)d_in[2];
    const float* Wk = (const float*)d_in[3];
    const float* Wv = (const float*)d_in[4];
    const float* Wo = (const float*)d_in[5];
    float* out = (float*)d_out;
    char*  ws  = (char*)d_ws;

    // ws layout:
    //  [0,8MB)     : bf16 weights Wq(scaled),Wk,Wv,Wo (Wk:Wv contiguous = fused B)
    //  [8,12MB)    : Qa  2048x1024 bf16
    //  [12,16MB)   : Om  2048x1024 bf16 (rows 0..1984 used)
    //  [16,80MB)   : Ka  32768x1024 bf16
    //  [80,144MB)  : Vt  1024x32768 bf16
    //  [144,208MB) : Anb 32768x1024 bf16   (fast path only)
    //  [208,212MB) : xb  2048x1024 bf16    (fast path only)
    if (ws_size < (size_t)144*1024*1024) return;
    const bool big = ws_size >= (size_t)212*1024*1024;
    u16* wW  = (u16*)ws;
    u16* Qa  = (u16*)(ws + (size_t) 8*1024*1024);
    u16* Om  = (u16*)(ws + (size_t)12*1024*1024);
    u16* Ka  = (u16*)(ws + (size_t)16*1024*1024);
    u16* Vt  = (u16*)(ws + (size_t)80*1024*1024);
    u16* Anb = (u16*)(ws + (size_t)144*1024*1024);
    u16* xb  = (u16*)(ws + (size_t)208*1024*1024);
    u16* wWq = wW, *wWk = wW + 1048576, *wWo = wW + 3*1048576;

    convert_w<<<dim3(4096), dim3(256), 0, stream>>>(Wq, Wk, Wv, Wo, wW);

    if (big) {
        convert_a<<<dim3(2048), dim3(256), 0, stream>>>(nb, Anb, 4194304);
        convert_a<<<dim3(512),  dim3(256), 0, stream>>>(x,  xb,  262144);
        // Q projection: 2048x1024, 16x8 tiles (128-tile kernel)
        gemm128<false, 0><<<dim3(128), dim3(256), 0, stream>>>(
            xb, 1024, wWq, 1024, Qa, nullptr, 2048, 1024, 0, 8);
        // fused K+V projection: 32768x2048, 128x8 256-tiles, 2-phase schedule
        gemm256<3><<<dim3(1024), dim3(512), 0, stream>>>(
            Anb, 1024, wWk, 1024, Ka, Vt, 32768, 1024, 8);
    } else {
        gemm128<true, 0><<<dim3(128), dim3(256), 0, stream>>>(
            x, 1024, wWq, 1024, Qa, nullptr, 2048, 1024, 0, 8);
        gemm128<true, 3><<<dim3(4096), dim3(256), 0, stream>>>(
            nb, 1024, wWk, 1024, Ka, Vt, 32768, 1024, 0, 16);
    }

    attn_kernel<<<dim3(31, 16), dim3(256), 0, stream>>>(Qa, Ka, Vt, Om);
    last_kernel<<<dim3(256),    dim3(256), 0, stream>>>(Vt, Om);

    gemm128<false, 2><<<dim3(128), dim3(256), 0, stream>>>(
        Om, 1024, wWo, 1024, out, nullptr, 1985, 1024, 63, 8);
    copy_head<<<dim3(63), dim3(256), 0, stream>>>(x, out);
}

// Round 9
// 267.761 us; speedup vs baseline: 1.0192x; 1.0192x over previous
//
#include <hip/hip_runtime.h>
#include <hip/hip_bf16.h>

// ChunkedCrossAttention (RETRO-style), MI355X gfx950.
// N=2048 M=64 K=2 R=512 D=1024 H=16 DH=64 LCH=32
//
// Round 9: revert gemm256 to round-7 4-phase loop (best) with split waits:
// vmcnt(4) at ph1-end (drains A1(t), 2-phase slack) and vmcnt(4) at ph4-end
// (drains B1/A0(t+1)); round-7's single vmcnt(2)@ph4 forced A1(t+1) with only
// 1 phase slack -> ~300cy/tile stall. Stage slots unchanged. attn: V loads
// hoisted to iteration top (explicit ILP).

using u16 = unsigned short;
using u32 = unsigned int;

typedef float  f32x4   __attribute__((ext_vector_type(4)));
typedef __bf16 bf16x8v __attribute__((ext_vector_type(8)));
typedef __bf16 bf16x4v __attribute__((ext_vector_type(4)));
typedef short  s16x4   __attribute__((ext_vector_type(4)));
typedef u16    u16x8   __attribute__((ext_vector_type(8)));
typedef u16    u16x4v  __attribute__((ext_vector_type(4)));

#define SCALE_LOG2E (1.4426950408889634f / 32.0f)

__device__ __forceinline__ u16 f2b(float f){ return __builtin_bit_cast(u16, (__bf16)f); }
// XOR swizzle on 16B slots within 128B LDS rows
__device__ __forceinline__ int swz(int row, int cb){ return row*128 + (cb ^ ((row & 7) << 4)); }

// async global->LDS, 16B per lane, wave-uniform LDS base (guide §5 / m97)
__device__ __forceinline__ void gl_lds16(const void* g, void* l) {
    __builtin_amdgcn_global_load_lds(
        (const __attribute__((address_space(1))) unsigned int*)(unsigned long long)g,
        (__attribute__((address_space(3))) unsigned int*)(unsigned int)(unsigned long long)l,
        16, 0, 0);
}

// ===========================================================================
// 256x256 4-phase GEMM (KV projection): C(MxN) = A(MxKc) @ B(NxKc)^T, bf16.
// OM=3 epilogue: bn<1024 -> Ka row-major (ld 1024); bn>=1024 -> Vt^T via LDS
// transpose, coalesced 16B stores.
// 512 threads = 8 waves (2M x 4N), per-wave 128x64 output, BK=64, NT=Kc/64.
// LDS 128KB: A dbuf[2] x half[2] x 16KB at [0,64K); B same at [64K,128K).
// Stage slots: ph1(t)->B1(t+1), ph2(t)->A0(t+1), ph3(t)->A1(t+1), ph4(t)->B0(t+2).
// Waits (each between MFMA and closing barrier, so the barrier publishes
// across waves — vmcnt is per-wave):
//   ph1-end: vmcnt(4) [drains A1(t), staged t-1 ph3, 2-phase slack]
//   ph4-end: vmcnt(4) [drains B1,A0(t+1); keeps A1(t+1), B0(t+2)]
// Tail guards: t=NT-2 ph4 -> vmcnt(2); t=NT-1 ph1 -> vmcnt(0), ph4 -> none.
// ===========================================================================
template<int OM>
__global__ __launch_bounds__(512, 2)
void gemm256(const u16* __restrict__ Ap, int lda,
             const u16* __restrict__ Bp, int ldb,
             void* __restrict__ Cp, void* __restrict__ Cp2,
             int M, int Kc, int nNt)
{
    __shared__ char Ls[131072];
    char* const Abase = Ls;
    char* const Bbase = Ls + 65536;

    const int tid  = threadIdx.x;
    const int lane = tid & 63, wave = tid >> 6;
    const int li = lane & 15, lg = lane >> 4;
    const int wr = wave >> 2, wc = wave & 3;

    const int nwg  = gridDim.x;
    const int lin  = blockIdx.x;
    const int lin2 = (lin & 7) * (nwg >> 3) + (lin >> 3);   // XCD chunk swizzle
    const long bm = (long)(lin2 / nNt) * 256;
    const long bn = (long)(lin2 % nNt) * 256;

    // staging geometry: 512 threads x 16B = 8KB = 64 rows/issue; 2 issues/half-tile
    const int srow = tid >> 3;                         // 0..63
    const int scol = ((tid & 7) ^ (srow & 7)) << 3;    // pre-swizzled col (elems)

    auto stageA = [&](int t, int hh) {
        char* d = Abase + (t & 1)*32768 + hh*16384 + wave*1024;
        long r0 = bm + hh*128 + srow;      if (r0 >= M) r0 = M - 1;
        long r1 = bm + hh*128 + 64 + srow; if (r1 >= M) r1 = M - 1;
        gl_lds16(Ap + r0*(long)lda + (long)t*64 + scol, d);
        gl_lds16(Ap + r1*(long)lda + (long)t*64 + scol, d + 8192);
    };
    auto stageB = [&](int t, int hh) {
        char* d = Bbase + (t & 1)*32768 + hh*16384 + wave*1024;
        long r0 = bn + hh*128 + srow;
        gl_lds16(Bp + r0*(long)ldb + (long)t*64 + scol, d);
        gl_lds16(Bp + (r0 + 64)*(long)ldb + (long)t*64 + scol, d + 8192);
    };

    const int NT = Kc >> 6;

    // prologue: B0(0),B1(0),A0(0) [6] + A1(0) [8] + B0(1) [10];
    // vmcnt(4) drains the first 6 (everything t=0 ph1 reads), barrier publishes.
    stageB(0, 0); stageB(0, 1); stageA(0, 0);
    stageA(0, 1); stageB(1, 0);
    asm volatile("s_waitcnt vmcnt(4)" ::: "memory");
    asm volatile("s_barrier" ::: "memory");

    // read-side per-thread constants
    const int swx = (li & 7) << 4;
    const int cb0 = (lg*16) ^ swx;          // k-step 0 column bytes (swizzled)
    const int cb1 = (64 + lg*16) ^ swx;     // k-step 1
    const int arb = li;                     // + mh*64 + mt*16, within wr half
    const int brb = (wc & 1)*64 + li;       // + nt*16, within wc>>1 half

    f32x4 acc[8][4] = {};
    bf16x8v a[4], b[4];

#define MFMA16(MH)                                                              \
    __builtin_amdgcn_s_setprio(1);                                              \
    _Pragma("unroll") for (int mt = 0; mt < 4; mt++)                            \
        _Pragma("unroll") for (int nt = 0; nt < 4; nt++)                        \
            acc[(MH)*4 + mt][nt] = __builtin_amdgcn_mfma_f32_16x16x32_bf16(     \
                a[mt], b[nt], acc[(MH)*4 + mt][nt], 0, 0, 0);                   \
    __builtin_amdgcn_s_setprio(0);

#define BAR_IN()  asm volatile("s_barrier" ::: "memory");                       \
                  asm volatile("s_waitcnt lgkmcnt(0)" ::: "memory");            \
                  __builtin_amdgcn_sched_barrier(0);
#define BAR_OUT() asm volatile("s_barrier" ::: "memory");

    for (int t = 0; t < NT; ++t) {
        char* At = Abase + (t & 1)*32768 + wr*16384;
        char* Bt = Bbase + (t & 1)*32768 + (wc >> 1)*16384;

        // ---- ph1: (mh0, k0), reads A0+B, stage B1(t+1) | wait: A1(t)
        #pragma unroll
        for (int mt = 0; mt < 4; mt++) a[mt] = *(const bf16x8v*)(At + (arb + mt*16)*128 + cb0);
        #pragma unroll
        for (int nt = 0; nt < 4; nt++) b[nt] = *(const bf16x8v*)(Bt + (brb + nt*16)*128 + cb0);
        if (t + 1 < NT) stageB(t + 1, 1);
        BAR_IN(); MFMA16(0);
        if (t + 1 < NT) { asm volatile("s_waitcnt vmcnt(4)" ::: "memory"); }
        else            { asm volatile("s_waitcnt vmcnt(0)" ::: "memory"); }
        BAR_OUT();
        // ---- ph2: (mh1, k0), reads A1, stage A0(t+1)
        #pragma unroll
        for (int mt = 0; mt < 4; mt++) a[mt] = *(const bf16x8v*)(At + (arb + 64 + mt*16)*128 + cb0);
        if (t + 1 < NT) stageA(t + 1, 0);
        BAR_IN(); MFMA16(1); BAR_OUT();
        // ---- ph3: (mh0, k1), reads A0+B, stage A1(t+1)
        #pragma unroll
        for (int mt = 0; mt < 4; mt++) a[mt] = *(const bf16x8v*)(At + (arb + mt*16)*128 + cb1);
        #pragma unroll
        for (int nt = 0; nt < 4; nt++) b[nt] = *(const bf16x8v*)(Bt + (brb + nt*16)*128 + cb1);
        if (t + 1 < NT) stageA(t + 1, 1);
        BAR_IN(); MFMA16(0); BAR_OUT();
        // ---- ph4: (mh1, k1), reads A1, stage B0(t+2) | wait: B1,A0(t+1)
        #pragma unroll
        for (int mt = 0; mt < 4; mt++) a[mt] = *(const bf16x8v*)(At + (arb + 64 + mt*16)*128 + cb1);
        if (t + 2 < NT) stageB(t + 2, 0);
        BAR_IN(); MFMA16(1);
        if      (t + 2 < NT) { asm volatile("s_waitcnt vmcnt(4)" ::: "memory"); }
        else if (t + 1 < NT) { asm volatile("s_waitcnt vmcnt(2)" ::: "memory"); }
        BAR_OUT();
    }
#undef MFMA16
#undef BAR_IN
#undef BAR_OUT

    if (OM == 3 && bn >= 1024) {
        // --- V-block epilogue: LDS transpose -> coalesced Vt stores ---
        // After final barrier all staged-LDS reads are drained; Ls is free.
        u16* Vt = (u16*)Cp2;
        #pragma unroll
        for (int ai = 0; ai < 8; ai++) {
            const int m0 = wr*128 + (ai >> 2)*64 + (ai & 3)*16 + lg*4;   // 4-aligned
            #pragma unroll
            for (int nt = 0; nt < 4; nt++) {
                const int n = wc*64 + nt*16 + li;
                f32x4 c = acc[ai][nt];
                bf16x4v w;
                #pragma unroll
                for (int j = 0; j < 4; j++) w[j] = (__bf16)c[j];
                // [n][m] tile, 512B rows; 16B-granule XOR swizzle by n
                *(bf16x4v*)(Ls + n*512 + ((m0*2) ^ ((n & 31) << 4))) = w;
            }
        }
        __syncthreads();
        const int n    = tid >> 1;              // Vt-local row 0..255
        const int half = (tid & 1) * 128;       // m half
        u16* dst = Vt + (bn - 1024 + n)*32768L + bm + half;
        #pragma unroll
        for (int i = 0; i < 16; i++) {
            const int mb = (half + i*8) * 2;    // byte offset, 16B aligned
            uint4 v = *(const uint4*)(Ls + n*512 + (mb ^ ((n & 31) << 4)));
            *(uint4*)(dst + i*8) = v;
        }
    } else if (OM == 3) {
        // --- K-block epilogue: row-major 2B stores ---
        u16* Ka = (u16*)Cp;
        #pragma unroll
        for (int ai = 0; ai < 8; ai++) {
            #pragma unroll
            for (int nt = 0; nt < 4; nt++) {
                f32x4 c = acc[ai][nt];
                const long row0 = bm + wr*128 + (ai >> 2)*64 + (ai & 3)*16 + lg*4;
                const long col  = bn + wc*64 + nt*16 + li;
                #pragma unroll
                for (int j = 0; j < 4; j++) {
                    long rg = row0 + j;
                    if (rg < M) Ka[rg*1024 + col] = f2b(c[j]);
                }
            }
        }
    }
}

// ---------------------------------------------------------------------------
// 128x128x64-step GEMM (Q/Wo projections + fallback), unchanged from round 3.
// ---------------------------------------------------------------------------
template<bool AF32, int OM>
__global__ __launch_bounds__(256)
void gemm128(const void* __restrict__ Ap, int lda,
             const u16* __restrict__ Bp, int ldb,
             void* __restrict__ Cp, void* __restrict__ Cp2,
             int M, int Kc, int row_off, int nNt)
{
    __shared__ char As[128*128];
    __shared__ char Bs[128*128];
    const int tid  = threadIdx.x;
    const int lane = tid & 63, wave = tid >> 6;
    const int li = lane & 15, lg = lane >> 4;
    const int wr = wave >> 1, wc = wave & 1;

    const int nwg  = gridDim.x;
    const int lin  = blockIdx.x;
    const int lin2 = (lin & 7) * (nwg >> 3) + (lin >> 3);
    const long bm = (long)(lin2 / nNt) * 128;
    const long bn = (long)(lin2 % nNt) * 128;

    const int grow = wave*32 + (lane >> 3);
    const int gcol = ((lane & 7) ^ (lane >> 3)) << 3;
    const int sr = tid >> 1, sc = (tid & 1) * 32;
    long arow_f = bm + sr; if (arow_f >= M) arow_f = M - 1;
    long arow_g[4];
    #pragma unroll
    for (int j = 0; j < 4; j++) {
        long r = bm + grow + j*8;
        arow_g[j] = (r < M) ? r : (M - 1);
    }

    f32x4 acc[4][4] = {};

    for (int k0 = 0; k0 < Kc; k0 += 64) {
        float4 a4[8];
        if (AF32) {
            const float4* ap = (const float4*)((const float*)Ap + arow_f*lda + k0 + sc);
            #pragma unroll
            for (int i = 0; i < 8; i++) a4[i] = ap[i];
        }
        __syncthreads();
        if (!AF32) {
            #pragma unroll
            for (int j = 0; j < 4; j++)
                gl_lds16((const u16*)Ap + arow_g[j]*(long)lda + k0 + gcol,
                         As + (wave*4 + j)*1024);
        }
        #pragma unroll
        for (int j = 0; j < 4; j++)
            gl_lds16(Bp + (bn + grow + j*8)*(long)ldb + k0 + gcol,
                     Bs + (wave*4 + j)*1024);
        if (AF32) {
            #pragma unroll
            for (int i = 0; i < 4; i++) {
                float4 f0 = a4[2*i], f1 = a4[2*i+1];
                bf16x8v w;
                w[0]=(__bf16)f0.x; w[1]=(__bf16)f0.y; w[2]=(__bf16)f0.z; w[3]=(__bf16)f0.w;
                w[4]=(__bf16)f1.x; w[5]=(__bf16)f1.y; w[6]=(__bf16)f1.z; w[7]=(__bf16)f1.w;
                *(bf16x8v*)(As + swz(sr, sc*2 + i*16)) = w;
            }
        }
        __syncthreads();
        #pragma unroll
        for (int es = 0; es < 2; es++) {
            bf16x8v af[4], bfv[4];
            #pragma unroll
            for (int mt = 0; mt < 4; mt++)
                af[mt] = *(const bf16x8v*)(As + swz(wr*64 + mt*16 + li, es*64 + lg*16));
            #pragma unroll
            for (int nt = 0; nt < 4; nt++)
                bfv[nt] = *(const bf16x8v*)(Bs + swz(wc*64 + nt*16 + li, es*64 + lg*16));
            #pragma unroll
            for (int mt = 0; mt < 4; mt++)
                #pragma unroll
                for (int nt = 0; nt < 4; nt++)
                    acc[mt][nt] = __builtin_amdgcn_mfma_f32_16x16x32_bf16(
                        af[mt], bfv[nt], acc[mt][nt], 0, 0, 0);
        }
    }

    #pragma unroll
    for (int mt = 0; mt < 4; mt++) {
        #pragma unroll
        for (int nt = 0; nt < 4; nt++) {
            f32x4 c = acc[mt][nt];
            const long row0 = bm + wr*64 + mt*16 + lg*4;
            const long col  = bn + wc*64 + nt*16 + li;
            if (OM == 0) {
                u16* C = (u16*)Cp;
                #pragma unroll
                for (int j = 0; j < 4; j++) {
                    long rg = row0 + j;
                    if (rg < M) C[rg*1024 + col] = f2b(c[j]);
                }
            } else if (OM == 2) {
                float* C = (float*)Cp;
                #pragma unroll
                for (int j = 0; j < 4; j++) {
                    long rg = row0 + j;
                    if (rg < M) C[(row_off + rg)*1024 + col] = c[j];
                }
            } else {
                if (col < 1024) {
                    u16* Ka = (u16*)Cp;
                    #pragma unroll
                    for (int j = 0; j < 4; j++) Ka[(row0 + j)*1024 + col] = f2b(c[j]);
                } else {
                    u16* Vt = (u16*)Cp2;
                    bf16x4v w;
                    #pragma unroll
                    for (int j = 0; j < 4; j++) w[j] = (__bf16)c[j];
                    *(bf16x4v*)(Vt + (col - 1024)*32768L + row0) = w;
                }
            }
        }
    }
}

// ---------------------------------------------------------------------------
// Attention: grid (31, 16) = (chunk u, head h), 4 waves stride 64 substeps.
// V loads hoisted to iteration top: all 6 global loads issue before QK^T,
// so V latency hides under QK MFMA + softmax VALU (explicit ILP; ~2 blocks/CU
// gives little TLP).
// ---------------------------------------------------------------------------
__global__ __launch_bounds__(256)
void attn_kernel(const u16* __restrict__ Qa, const u16* __restrict__ Ka,
                 const u16* __restrict__ Vt, u16* __restrict__ Om)
{
    const int u = blockIdx.x, h = blockIdx.y;
    const int tid = threadIdx.x;
    const int lane = tid & 63, wave = tid >> 6;
    const int li = lane & 15, lg = lane >> 4;

    bf16x8v qf[4][2];
    #pragma unroll
    for (int qt = 0; qt < 4; qt++)
        #pragma unroll
        for (int es = 0; es < 2; es++)
            qf[qt][es] = *(const bf16x8v*)(Qa + (long)(63 + u*64 + qt*16 + li)*1024
                                              + h*64 + es*32 + lg*8);

    f32x4 acc[4][4] = {};

    for (int it = wave; it < 64; it += 4) {
        const int k = it >> 5, rsub = it & 31;
        const long kr = (long)u*1024 + k*512 + rsub*16;

        bf16x8v a0 = *(const bf16x8v*)(Ka + (kr + li)*1024 + h*64 + lg*8);
        bf16x8v a1 = *(const bf16x8v*)(Ka + (kr + li)*1024 + h*64 + 32 + lg*8);
        s16x4 va[4];
        #pragma unroll
        for (int et = 0; et < 4; et++)
            va[et] = *(const s16x4*)(Vt + (long)(h*64 + et*16 + li)*32768 + kr + lg*4);

        f32x4 s[4];
        #pragma unroll
        for (int qt = 0; qt < 4; qt++) {
            f32x4 c = {};
            c = __builtin_amdgcn_mfma_f32_16x16x32_bf16(a0, qf[qt][0], c, 0, 0, 0);
            c = __builtin_amdgcn_mfma_f32_16x16x32_bf16(a1, qf[qt][1], c, 0, 0, 0);
            s[qt] = c;
        }
        float p[4][4];
        #pragma unroll
        for (int qt = 0; qt < 4; qt++)
            #pragma unroll
            for (int j = 0; j < 4; j++)
                p[qt][j] = __builtin_amdgcn_exp2f(s[qt][j]);
        float rz[4];
        #pragma unroll
        for (int j = 0; j < 4; j++) {
            float z = p[0][j] + p[1][j] + p[2][j] + p[3][j];
            z += __shfl_xor(z, 1); z += __shfl_xor(z, 2);
            z += __shfl_xor(z, 4); z += __shfl_xor(z, 8);
            rz[j] = __builtin_amdgcn_rcpf(z);
        }
        s16x4 wf[4];
        #pragma unroll
        for (int qt = 0; qt < 4; qt++) {
            bf16x4v w;
            #pragma unroll
            for (int j = 0; j < 4; j++) w[j] = (__bf16)(p[qt][j] * rz[j]);
            wf[qt] = __builtin_bit_cast(s16x4, w);
        }
        #pragma unroll
        for (int et = 0; et < 4; et++)
            #pragma unroll
            for (int qt = 0; qt < 4; qt++)
                acc[et][qt] = __builtin_amdgcn_mfma_f32_16x16x16bf16_1k(
                    va[et], wf[qt], acc[et][qt], 0, 0, 0);
    }

    __shared__ float Osum[64*64];
    for (int w = 0; w < 4; w++) {
        if (wave == w) {
            #pragma unroll
            for (int et = 0; et < 4; et++)
                #pragma unroll
                for (int qt = 0; qt < 4; qt++)
                    #pragma unroll
                    for (int j = 0; j < 4; j++) {
                        int e = et*16 + lg*4 + j, q = qt*16 + li;
                        if (w == 0) Osum[e*64 + q]  = acc[et][qt][j];
                        else        Osum[e*64 + q] += acc[et][qt][j];
                    }
        }
        __syncthreads();
    }
    const int q = tid & 63, e0 = (tid >> 6) * 16;
    u16x8 o0, o1;
    #pragma unroll
    for (int i = 0; i < 8; i++) {
        o0[i] = f2b(0.5f * Osum[(e0 + i    )*64 + q]);
        o1[i] = f2b(0.5f * Osum[(e0 + 8 + i)*64 + q]);
    }
    u16* dst = Om + (long)(u*64 + q)*1024 + h*64 + e0;
    *(u16x8*)dst       = o0;
    *(u16x8*)(dst + 8) = o1;
}

// ---------------------------------------------------------------------------
__global__ __launch_bounds__(256)
void convert_w(const float* __restrict__ Wq, const float* __restrict__ Wk,
               const float* __restrict__ Wv, const float* __restrict__ Wo,
               u16* __restrict__ dst)
{
    int idx = blockIdx.x*256 + threadIdx.x;
    int w   = idx >> 18;
    int off = (idx & 262143) << 2;
    const float* src = (w == 0) ? Wq : (w == 1) ? Wk : (w == 2) ? Wv : Wo;
    float scv = (w == 0) ? SCALE_LOG2E : 1.0f;
    float4 v = *(const float4*)(src + off);
    u16x4v o = { f2b(v.x*scv), f2b(v.y*scv), f2b(v.z*scv), f2b(v.w*scv) };
    *(u16x4v*)(dst + (long)w*1048576 + off) = o;
}

__global__ __launch_bounds__(256)
void convert_a(const float* __restrict__ src, u16* __restrict__ dst, int n8)
{
    int i = blockIdx.x*256 + threadIdx.x;
    const int stride = gridDim.x*256;
    for (; i < n8; i += stride) {
        float4 f0 = ((const float4*)src)[2*i], f1 = ((const float4*)src)[2*i+1];
        u16x8 o = { f2b(f0.x), f2b(f0.y), f2b(f0.z), f2b(f0.w),
                    f2b(f1.x), f2b(f1.y), f2b(f1.z), f2b(f1.w) };
        ((u16x8*)dst)[i] = o;
    }
}

__global__ __launch_bounds__(256)
void last_kernel(const u16* __restrict__ Vt, u16* __restrict__ Om)
{
    const int row  = blockIdx.x*4 + (threadIdx.x >> 6);
    const int lane = threadIdx.x & 63;
    const u16* p = Vt + (long)row*32768 + 31*1024 + lane*16;
    float s = 0.f;
    #pragma unroll
    for (int hf = 0; hf < 2; hf++) {
        bf16x8v v = *(const bf16x8v*)(p + hf*8);
        #pragma unroll
        for (int i = 0; i < 8; i++) s += (float)v[i];
    }
    #pragma unroll
    for (int m = 1; m < 64; m <<= 1) s += __shfl_xor(s, m);
    if (lane == 0) Om[(long)1984*1024 + row] = f2b(0.5f * s);
}

__global__ __launch_bounds__(256)
void copy_head(const float* __restrict__ x, float* __restrict__ out)
{
    int i = blockIdx.x*256 + threadIdx.x;
    ((float4*)out)[i] = ((const float4*)x)[i];
}

// ---------------------------------------------------------------------------
extern "C" void kernel_launch(void* const* d_in, const int* in_sizes, int n_in,
                              void* d_out, int out_size, void* d_ws, size_t ws_size,
                              hipStream_t stream)
{
    const float* x  = (const float*)d_in[0];
    const float* nb = (const float*)d_in[1];
    const float* Wq = (const float*)d_in[2];
    const float* Wk = (const float*)d_in[3];
    const float* Wv = (const float*)d_in[4];
    const float* Wo = (const float*)d_in[5];
    float* out = (float*)d_out;
    char*  ws  = (char*)d_ws;

    // ws layout:
    //  [0,8MB)     : bf16 weights Wq(scaled),Wk,Wv,Wo (Wk:Wv contiguous = fused B)
    //  [8,12MB)    : Qa  2048x1024 bf16
    //  [12,16MB)   : Om  2048x1024 bf16 (rows 0..1984 used)
    //  [16,80MB)   : Ka  32768x1024 bf16
    //  [80,144MB)  : Vt  1024x32768 bf16
    //  [144,208MB) : Anb 32768x1024 bf16   (fast path only)
    //  [208,212MB) : xb  2048x1024 bf16    (fast path only)
    if (ws_size < (size_t)144*1024*1024) return;
    const bool big = ws_size >= (size_t)212*1024*1024;
    u16* wW  = (u16*)ws;
    u16* Qa  = (u16*)(ws + (size_t) 8*1024*1024);
    u16* Om  = (u16*)(ws + (size_t)12*1024*1024);
    u16* Ka  = (u16*)(ws + (size_t)16*1024*1024);
    u16* Vt  = (u16*)(ws + (size_t)80*1024*1024);
    u16* Anb = (u16*)(ws + (size_t)144*1024*1024);
    u16* xb  = (u16*)(ws + (size_t)208*1024*1024);
    u16* wWq = wW, *wWk = wW + 1048576, *wWo = wW + 3*1048576;

    convert_w<<<dim3(4096), dim3(256), 0, stream>>>(Wq, Wk, Wv, Wo, wW);

    if (big) {
        convert_a<<<dim3(2048), dim3(256), 0, stream>>>(nb, Anb, 4194304);
        convert_a<<<dim3(512),  dim3(256), 0, stream>>>(x,  xb,  262144);
        // Q projection: 2048x1024, 16x8 tiles (128-tile kernel)
        gemm128<false, 0><<<dim3(128), dim3(256), 0, stream>>>(
            xb, 1024, wWq, 1024, Qa, nullptr, 2048, 1024, 0, 8);
        // fused K+V projection: 32768x2048, 128x8 256-tiles, 4-phase schedule
        gemm256<3><<<dim3(1024), dim3(512), 0, stream>>>(
            Anb, 1024, wWk, 1024, Ka, Vt, 32768, 1024, 8);
    } else {
        gemm128<true, 0><<<dim3(128), dim3(256), 0, stream>>>(
            x, 1024, wWq, 1024, Qa, nullptr, 2048, 1024, 0, 8);
        gemm128<true, 3><<<dim3(4096), dim3(256), 0, stream>>>(
            nb, 1024, wWk, 1024, Ka, Vt, 32768, 1024, 0, 16);
    }

    attn_kernel<<<dim3(31, 16), dim3(256), 0, stream>>>(Qa, Ka, Vt, Om);
    last_kernel<<<dim3(256),    dim3(256), 0, stream>>>(Vt, Om);

    gemm128<false, 2><<<dim3(128), dim3(256), 0, stream>>>(
        Om, 1024, wWo, 1024, out, nullptr, 1985, 1024, 63, 8);
    copy_head<<<dim3(63), dim3(256), 0, stream>>>(x, out);
}

// Round 10
// 257.011 us; speedup vs baseline: 1.0619x; 1.0418x over previous
//
#include <hip/hip_runtime.h>
#include <hip/hip_bf16.h>

// ChunkedCrossAttention (RETRO-style), MI355X gfx950.
// N=2048 M=64 K=2 R=512 D=1024 H=16 DH=64 LCH=32
//
// Round 10: gemm256 K-loop rebuilt: 2 barriers/tile, issue-ahead ds_reads
// with compiler-counted lgkm waits (LDS reads overlap MFMA), register-reused
// operand sets, precomputed per-lane stage pointers (no clamps, no per-call
// 64-bit muls). Converts merged into one kernel.

using u16 = unsigned short;
using u32 = unsigned int;

typedef float  f32x4   __attribute__((ext_vector_type(4)));
typedef __bf16 bf16x8v __attribute__((ext_vector_type(8)));
typedef __bf16 bf16x4v __attribute__((ext_vector_type(4)));
typedef short  s16x4   __attribute__((ext_vector_type(4)));
typedef u16    u16x8   __attribute__((ext_vector_type(8)));
typedef u16    u16x4v  __attribute__((ext_vector_type(4)));

#define SCALE_LOG2E (1.4426950408889634f / 32.0f)

__device__ __forceinline__ u16 f2b(float f){ return __builtin_bit_cast(u16, (__bf16)f); }
// XOR swizzle on 16B slots within 128B LDS rows
__device__ __forceinline__ int swz(int row, int cb){ return row*128 + (cb ^ ((row & 7) << 4)); }

// async global->LDS, 16B per lane, wave-uniform LDS base (guide §5 / m97)
__device__ __forceinline__ void gl_lds16(const void* g, void* l) {
    __builtin_amdgcn_global_load_lds(
        (const __attribute__((address_space(1))) unsigned int*)(unsigned long long)g,
        (__attribute__((address_space(3))) unsigned int*)(unsigned int)(unsigned long long)l,
        16, 0, 0);
}

// ===========================================================================
// 256x256 GEMM (KV projection): C(MxN) = A(MxKc) @ B(NxKc)^T, bf16.
// REQUIRES M % 256 == 0 (no row clamps). OM=3 epilogue: bn<1024 -> Ka
// row-major; bn>=1024 -> Vt^T via LDS transpose, coalesced stores.
// 512 threads = 8 waves (2M x 4N), per-wave 128x64 output, BK=64, NT=Kc/64.
// LDS 128KB: A dbuf[2] x half[2] x 16KB at [0,64K); B same at [64K,128K).
// Per tile t (2 barriers):
//   [RD a,b@k0 | stage B1,A0(t+1) | RD a1@k0] MFMA00
//   [stage A1(t+1) | RD a@k1] MFMA10  [RD b,a1@k1] MFMA01
//   MID barrier (all waves consumed b@k1 -> B0 region free)
//   stage B0(t+2); MFMA11; vmcnt(2) [t+1 landed]; END barrier (publish)
// Compiler inserts counted lgkmcnt(4) before each MFMA (deps tracked in C++),
// so ds_reads execute during MFMA. vmcnt guards: s2->2, else s1->0, else none.
// ===========================================================================
template<int OM>
__global__ __launch_bounds__(512, 2)
void gemm256(const u16* __restrict__ Ap, int lda,
             const u16* __restrict__ Bp, int ldb,
             void* __restrict__ Cp, void* __restrict__ Cp2,
             int M, int Kc, int nNt)
{
    __shared__ char Ls[131072];
    char* const Abase = Ls;
    char* const Bbase = Ls + 65536;

    const int tid  = threadIdx.x;
    const int lane = tid & 63, wave = tid >> 6;
    const int li = lane & 15, lg = lane >> 4;
    const int wr = wave >> 2, wc = wave & 3;

    const int nwg  = gridDim.x;
    const int lin  = blockIdx.x;
    const int lin2 = (lin & 7) * (nwg >> 3) + (lin >> 3);   // XCD chunk swizzle
    const long bm = (long)(lin2 / nNt) * 256;
    const long bn = (long)(lin2 % nNt) * 256;

    // staging geometry: 512 threads x 16B = 8KB = 64 rows/issue; 2 issues/half-tile
    const int srow = tid >> 3;                         // 0..63
    const int scol = ((tid & 7) ^ (srow & 7)) << 3;    // pre-swizzled col (elems)

    // precomputed per-lane global stage pointers (M,N % 256 == 0: no clamps)
    const u16* const pA0 = Ap + (bm + srow)*(long)lda + scol;
    const u16* const pA1 = Ap + (bm + 128 + srow)*(long)lda + scol;
    const u16* const pB0 = Bp + (bn + srow)*(long)ldb + scol;
    const u16* const pB1 = Bp + (bn + 128 + srow)*(long)ldb + scol;
    const long l64a = 64*(long)lda, l64b = 64*(long)ldb;

    auto stA = [&](int t, int hh) {
        char* d = Abase + (t & 1)*32768 + hh*16384 + wave*1024;
        const u16* p = (hh ? pA1 : pA0) + (long)t*64;
        gl_lds16(p, d);
        gl_lds16(p + l64a, d + 8192);
    };
    auto stB = [&](int t, int hh) {
        char* d = Bbase + (t & 1)*32768 + hh*16384 + wave*1024;
        const u16* p = (hh ? pB1 : pB0) + (long)t*64;
        gl_lds16(p, d);
        gl_lds16(p + l64b, d + 8192);
    };

    const int NT = Kc >> 6;

    // prologue: tile0 (8 loads) + B0(1) (2) = 10; vmcnt(2) -> tile0 landed
    stB(0, 0); stB(0, 1); stA(0, 0); stA(0, 1); stB(1, 0);
    asm volatile("s_waitcnt vmcnt(2)" ::: "memory");
    asm volatile("s_barrier" ::: "memory");

    // read-side per-thread constants
    const int swx = (li & 7) << 4;
    const int cb0 = (lg*16) ^ swx;          // k-step 0 column bytes (swizzled)
    const int cb1 = (64 + lg*16) ^ swx;     // k-step 1
    const int brb = (wc & 1)*64 + li;       // B row within wc>>1 half

    f32x4 acc[8][4] = {};
    bf16x8v av[4], aw[4], bv[4];

#define MFMA16(MH, AA, BB)                                                      \
    __builtin_amdgcn_s_setprio(1);                                              \
    _Pragma("unroll") for (int mt = 0; mt < 4; mt++)                            \
        _Pragma("unroll") for (int nt = 0; nt < 4; nt++)                        \
            acc[(MH)*4 + mt][nt] = __builtin_amdgcn_mfma_f32_16x16x32_bf16(     \
                (AA)[mt], (BB)[nt], acc[(MH)*4 + mt][nt], 0, 0, 0);             \
    __builtin_amdgcn_s_setprio(0);
#define RDA(DST, OFS, CB)                                                       \
    _Pragma("unroll") for (int i = 0; i < 4; i++)                               \
        (DST)[i] = *(const bf16x8v*)(At + (li + (OFS) + i*16)*128 + (CB));
#define RDB(DST, CB)                                                            \
    _Pragma("unroll") for (int i = 0; i < 4; i++)                               \
        (DST)[i] = *(const bf16x8v*)(Bt + (brb + i*16)*128 + (CB));

    for (int t = 0; t < NT; ++t) {
        char* At = Abase + (t & 1)*32768 + wr*16384;
        char* Bt = Bbase + (t & 1)*32768 + (wc >> 1)*16384;
        const bool s1 = (t + 1 < NT), s2 = (t + 2 < NT);

        // k0 half: issue all k0 reads + other-buffer stages, then MFMA
        RDA(av, 0, cb0); RDB(bv, cb0);
        if (s1) { stB(t + 1, 1); stA(t + 1, 0); }
        RDA(aw, 64, cb0);
        __builtin_amdgcn_sched_barrier(0);
        MFMA16(0, av, bv);                  // waits av,bv (aw outstanding -> counted)
        if (s1) stA(t + 1, 1);
        RDA(av, 0, cb1);                    // reuse av regs; hides under MFMA10
        __builtin_amdgcn_sched_barrier(0);
        MFMA16(1, aw, bv);                  // waits aw
        RDB(bv, cb1); RDA(aw, 64, cb1);     // reuse; hides under MFMA01 wait chain
        __builtin_amdgcn_sched_barrier(0);
        MFMA16(0, av, bv);                  // waits av(k1), bv(k1)
        asm volatile("s_barrier" ::: "memory");   // MID: all waves' b@k1 reads done
        if (s2) stB(t + 2, 0);                    // current-buffer B0, now free
        MFMA16(1, aw, bv);                  // waits aw(k1)
        if      (s2) { asm volatile("s_waitcnt vmcnt(2)" ::: "memory"); }
        else if (s1) { asm volatile("s_waitcnt vmcnt(0)" ::: "memory"); }
        asm volatile("s_barrier" ::: "memory");   // END: publish t+1 stages
    }
#undef MFMA16
#undef RDA
#undef RDB

    if (OM == 3 && bn >= 1024) {
        // --- V-block epilogue: LDS transpose -> coalesced Vt stores ---
        u16* Vt = (u16*)Cp2;
        #pragma unroll
        for (int ai = 0; ai < 8; ai++) {
            const int m0 = wr*128 + (ai >> 2)*64 + (ai & 3)*16 + lg*4;   // 4-aligned
            #pragma unroll
            for (int nt = 0; nt < 4; nt++) {
                const int n = wc*64 + nt*16 + li;
                f32x4 c = acc[ai][nt];
                bf16x4v w;
                #pragma unroll
                for (int j = 0; j < 4; j++) w[j] = (__bf16)c[j];
                *(bf16x4v*)(Ls + n*512 + ((m0*2) ^ ((n & 31) << 4))) = w;
            }
        }
        __syncthreads();
        const int n    = tid >> 1;              // Vt-local row 0..255
        const int half = (tid & 1) * 128;       // m half
        u16* dst = Vt + (bn - 1024 + n)*32768L + bm + half;
        #pragma unroll
        for (int i = 0; i < 16; i++) {
            const int mb = (half + i*8) * 2;    // byte offset, 16B aligned
            uint4 v = *(const uint4*)(Ls + n*512 + (mb ^ ((n & 31) << 4)));
            *(uint4*)(dst + i*8) = v;
        }
    } else if (OM == 3) {
        // --- K-block epilogue: row-major 2B stores ---
        u16* Ka = (u16*)Cp;
        #pragma unroll
        for (int ai = 0; ai < 8; ai++) {
            #pragma unroll
            for (int nt = 0; nt < 4; nt++) {
                f32x4 c = acc[ai][nt];
                const long row0 = bm + wr*128 + (ai >> 2)*64 + (ai & 3)*16 + lg*4;
                const long col  = bn + wc*64 + nt*16 + li;
                #pragma unroll
                for (int j = 0; j < 4; j++)
                    Ka[(row0 + j)*1024 + col] = f2b(c[j]);
            }
        }
    }
}

// ---------------------------------------------------------------------------
// 128x128x64-step GEMM (Q/Wo projections + fallback), unchanged.
// ---------------------------------------------------------------------------
template<bool AF32, int OM>
__global__ __launch_bounds__(256)
void gemm128(const void* __restrict__ Ap, int lda,
             const u16* __restrict__ Bp, int ldb,
             void* __restrict__ Cp, void* __restrict__ Cp2,
             int M, int Kc, int row_off, int nNt)
{
    __shared__ char As[128*128];
    __shared__ char Bs[128*128];
    const int tid  = threadIdx.x;
    const int lane = tid & 63, wave = tid >> 6;
    const int li = lane & 15, lg = lane >> 4;
    const int wr = wave >> 1, wc = wave & 1;

    const int nwg  = gridDim.x;
    const int lin  = blockIdx.x;
    const int lin2 = (lin & 7) * (nwg >> 3) + (lin >> 3);
    const long bm = (long)(lin2 / nNt) * 128;
    const long bn = (long)(lin2 % nNt) * 128;

    const int grow = wave*32 + (lane >> 3);
    const int gcol = ((lane & 7) ^ (lane >> 3)) << 3;
    const int sr = tid >> 1, sc = (tid & 1) * 32;
    long arow_f = bm + sr; if (arow_f >= M) arow_f = M - 1;
    long arow_g[4];
    #pragma unroll
    for (int j = 0; j < 4; j++) {
        long r = bm + grow + j*8;
        arow_g[j] = (r < M) ? r : (M - 1);
    }

    f32x4 acc[4][4] = {};

    for (int k0 = 0; k0 < Kc; k0 += 64) {
        float4 a4[8];
        if (AF32) {
            const float4* ap = (const float4*)((const float*)Ap + arow_f*lda + k0 + sc);
            #pragma unroll
            for (int i = 0; i < 8; i++) a4[i] = ap[i];
        }
        __syncthreads();
        if (!AF32) {
            #pragma unroll
            for (int j = 0; j < 4; j++)
                gl_lds16((const u16*)Ap + arow_g[j]*(long)lda + k0 + gcol,
                         As + (wave*4 + j)*1024);
        }
        #pragma unroll
        for (int j = 0; j < 4; j++)
            gl_lds16(Bp + (bn + grow + j*8)*(long)ldb + k0 + gcol,
                     Bs + (wave*4 + j)*1024);
        if (AF32) {
            #pragma unroll
            for (int i = 0; i < 4; i++) {
                float4 f0 = a4[2*i], f1 = a4[2*i+1];
                bf16x8v w;
                w[0]=(__bf16)f0.x; w[1]=(__bf16)f0.y; w[2]=(__bf16)f0.z; w[3]=(__bf16)f0.w;
                w[4]=(__bf16)f1.x; w[5]=(__bf16)f1.y; w[6]=(__bf16)f1.z; w[7]=(__bf16)f1.w;
                *(bf16x8v*)(As + swz(sr, sc*2 + i*16)) = w;
            }
        }
        __syncthreads();
        #pragma unroll
        for (int es = 0; es < 2; es++) {
            bf16x8v af[4], bfv[4];
            #pragma unroll
            for (int mt = 0; mt < 4; mt++)
                af[mt] = *(const bf16x8v*)(As + swz(wr*64 + mt*16 + li, es*64 + lg*16));
            #pragma unroll
            for (int nt = 0; nt < 4; nt++)
                bfv[nt] = *(const bf16x8v*)(Bs + swz(wc*64 + nt*16 + li, es*64 + lg*16));
            #pragma unroll
            for (int mt = 0; mt < 4; mt++)
                #pragma unroll
                for (int nt = 0; nt < 4; nt++)
                    acc[mt][nt] = __builtin_amdgcn_mfma_f32_16x16x32_bf16(
                        af[mt], bfv[nt], acc[mt][nt], 0, 0, 0);
        }
    }

    #pragma unroll
    for (int mt = 0; mt < 4; mt++) {
        #pragma unroll
        for (int nt = 0; nt < 4; nt++) {
            f32x4 c = acc[mt][nt];
            const long row0 = bm + wr*64 + mt*16 + lg*4;
            const long col  = bn + wc*64 + nt*16 + li;
            if (OM == 0) {
                u16* C = (u16*)Cp;
                #pragma unroll
                for (int j = 0; j < 4; j++) {
                    long rg = row0 + j;
                    if (rg < M) C[rg*1024 + col] = f2b(c[j]);
                }
            } else if (OM == 2) {
                float* C = (float*)Cp;
                #pragma unroll
                for (int j = 0; j < 4; j++) {
                    long rg = row0 + j;
                    if (rg < M) C[(row_off + rg)*1024 + col] = c[j];
                }
            } else {
                if (col < 1024) {
                    u16* Ka = (u16*)Cp;
                    #pragma unroll
                    for (int j = 0; j < 4; j++) Ka[(row0 + j)*1024 + col] = f2b(c[j]);
                } else {
                    u16* Vt = (u16*)Cp2;
                    bf16x4v w;
                    #pragma unroll
                    for (int j = 0; j < 4; j++) w[j] = (__bf16)c[j];
                    *(bf16x4v*)(Vt + (col - 1024)*32768L + row0) = w;
                }
            }
        }
    }
}

// ---------------------------------------------------------------------------
// Attention: grid (31, 16) = (chunk u, head h), 4 waves stride 64 substeps.
// ---------------------------------------------------------------------------
__global__ __launch_bounds__(256)
void attn_kernel(const u16* __restrict__ Qa, const u16* __restrict__ Ka,
                 const u16* __restrict__ Vt, u16* __restrict__ Om)
{
    const int u = blockIdx.x, h = blockIdx.y;
    const int tid = threadIdx.x;
    const int lane = tid & 63, wave = tid >> 6;
    const int li = lane & 15, lg = lane >> 4;

    bf16x8v qf[4][2];
    #pragma unroll
    for (int qt = 0; qt < 4; qt++)
        #pragma unroll
        for (int es = 0; es < 2; es++)
            qf[qt][es] = *(const bf16x8v*)(Qa + (long)(63 + u*64 + qt*16 + li)*1024
                                              + h*64 + es*32 + lg*8);

    f32x4 acc[4][4] = {};

    for (int it = wave; it < 64; it += 4) {
        const int k = it >> 5, rsub = it & 31;
        const long kr = (long)u*1024 + k*512 + rsub*16;

        bf16x8v a0 = *(const bf16x8v*)(Ka + (kr + li)*1024 + h*64 + lg*8);
        bf16x8v a1 = *(const bf16x8v*)(Ka + (kr + li)*1024 + h*64 + 32 + lg*8);
        s16x4 va[4];
        #pragma unroll
        for (int et = 0; et < 4; et++)
            va[et] = *(const s16x4*)(Vt + (long)(h*64 + et*16 + li)*32768 + kr + lg*4);

        f32x4 s[4];
        #pragma unroll
        for (int qt = 0; qt < 4; qt++) {
            f32x4 c = {};
            c = __builtin_amdgcn_mfma_f32_16x16x32_bf16(a0, qf[qt][0], c, 0, 0, 0);
            c = __builtin_amdgcn_mfma_f32_16x16x32_bf16(a1, qf[qt][1], c, 0, 0, 0);
            s[qt] = c;
        }
        float p[4][4];
        #pragma unroll
        for (int qt = 0; qt < 4; qt++)
            #pragma unroll
            for (int j = 0; j < 4; j++)
                p[qt][j] = __builtin_amdgcn_exp2f(s[qt][j]);
        float rz[4];
        #pragma unroll
        for (int j = 0; j < 4; j++) {
            float z = p[0][j] + p[1][j] + p[2][j] + p[3][j];
            z += __shfl_xor(z, 1); z += __shfl_xor(z, 2);
            z += __shfl_xor(z, 4); z += __shfl_xor(z, 8);
            rz[j] = __builtin_amdgcn_rcpf(z);
        }
        s16x4 wf[4];
        #pragma unroll
        for (int qt = 0; qt < 4; qt++) {
            bf16x4v w;
            #pragma unroll
            for (int j = 0; j < 4; j++) w[j] = (__bf16)(p[qt][j] * rz[j]);
            wf[qt] = __builtin_bit_cast(s16x4, w);
        }
        #pragma unroll
        for (int et = 0; et < 4; et++)
            #pragma unroll
            for (int qt = 0; qt < 4; qt++)
                acc[et][qt] = __builtin_amdgcn_mfma_f32_16x16x16bf16_1k(
                    va[et], wf[qt], acc[et][qt], 0, 0, 0);
    }

    __shared__ float Osum[64*64];
    for (int w = 0; w < 4; w++) {
        if (wave == w) {
            #pragma unroll
            for (int et = 0; et < 4; et++)
                #pragma unroll
                for (int qt = 0; qt < 4; qt++)
                    #pragma unroll
                    for (int j = 0; j < 4; j++) {
                        int e = et*16 + lg*4 + j, q = qt*16 + li;
                        if (w == 0) Osum[e*64 + q]  = acc[et][qt][j];
                        else        Osum[e*64 + q] += acc[et][qt][j];
                    }
        }
        __syncthreads();
    }
    const int q = tid & 63, e0 = (tid >> 6) * 16;
    u16x8 o0, o1;
    #pragma unroll
    for (int i = 0; i < 8; i++) {
        o0[i] = f2b(0.5f * Osum[(e0 + i    )*64 + q]);
        o1[i] = f2b(0.5f * Osum[(e0 + 8 + i)*64 + q]);
    }
    u16* dst = Om + (long)(u*64 + q)*1024 + h*64 + e0;
    *(u16x8*)dst       = o0;
    *(u16x8*)(dst + 8) = o1;
}

// ---------------------------------------------------------------------------
// merged f32->bf16 converts: weights (Wq scaled) + optionally nb and x.
// chunk = 8 elems. W: 524288 chunks, nb: 4194304, x: 262144.
// ---------------------------------------------------------------------------
__global__ __launch_bounds__(256)
void convert_all(const float* __restrict__ Wq, const float* __restrict__ Wk,
                 const float* __restrict__ Wv, const float* __restrict__ Wo,
                 const float* __restrict__ nb, const float* __restrict__ x,
                 u16* __restrict__ wW, u16* __restrict__ Anb,
                 u16* __restrict__ xb, int doA)
{
    const int NW = 524288, NN = 4194304, NX = 262144;
    const int tot = doA ? (NW + NN + NX) : NW;
    const int stride = gridDim.x*256;
    for (int i = blockIdx.x*256 + threadIdx.x; i < tot; i += stride) {
        const float* s; u16* d; float sc = 1.0f;
        if (i < NW) {
            int w = i >> 17;                       // 131072 chunks per weight
            long off = (long)(i & 131071) * 8;
            s = (w == 0) ? Wq : (w == 1) ? Wk : (w == 2) ? Wv : Wo;
            s += off;
            d = wW + (long)w*1048576 + off;
            if (w == 0) sc = SCALE_LOG2E;
        } else if (i < NW + NN) {
            long off = (long)(i - NW) * 8;
            s = nb + off; d = Anb + off;
        } else {
            long off = (long)(i - NW - NN) * 8;
            s = x + off; d = xb + off;
        }
        float4 f0 = ((const float4*)s)[0], f1 = ((const float4*)s)[1];
        u16x8 o = { f2b(f0.x*sc), f2b(f0.y*sc), f2b(f0.z*sc), f2b(f0.w*sc),
                    f2b(f1.x*sc), f2b(f1.y*sc), f2b(f1.z*sc), f2b(f1.w*sc) };
        *(u16x8*)d = o;
    }
}

__global__ __launch_bounds__(256)
void last_kernel(const u16* __restrict__ Vt, u16* __restrict__ Om)
{
    const int row  = blockIdx.x*4 + (threadIdx.x >> 6);
    const int lane = threadIdx.x & 63;
    const u16* p = Vt + (long)row*32768 + 31*1024 + lane*16;
    float s = 0.f;
    #pragma unroll
    for (int hf = 0; hf < 2; hf++) {
        bf16x8v v = *(const bf16x8v*)(p + hf*8);
        #pragma unroll
        for (int i = 0; i < 8; i++) s += (float)v[i];
    }
    #pragma unroll
    for (int m = 1; m < 64; m <<= 1) s += __shfl_xor(s, m);
    if (lane == 0) Om[(long)1984*1024 + row] = f2b(0.5f * s);
}

__global__ __launch_bounds__(256)
void copy_head(const float* __restrict__ x, float* __restrict__ out)
{
    int i = blockIdx.x*256 + threadIdx.x;
    ((float4*)out)[i] = ((const float4*)x)[i];
}

// ---------------------------------------------------------------------------
extern "C" void kernel_launch(void* const* d_in, const int* in_sizes, int n_in,
                              void* d_out, int out_size, void* d_ws, size_t ws_size,
                              hipStream_t stream)
{
    const float* x  = (const float*)d_in[0];
    const float* nb = (const float*)d_in[1];
    const float* Wq = (const float*)d_in[2];
    const float* Wk = (const float*)d_in[3];
    const float* Wv = (const float*)d_in[4];
    const float* Wo = (const float*)d_in[5];
    float* out = (float*)d_out;
    char*  ws  = (char*)d_ws;

    // ws layout:
    //  [0,8MB)     : bf16 weights Wq(scaled),Wk,Wv,Wo (Wk:Wv contiguous = fused B)
    //  [8,12MB)    : Qa  2048x1024 bf16
    //  [12,16MB)   : Om  2048x1024 bf16 (rows 0..1984 used)
    //  [16,80MB)   : Ka  32768x1024 bf16
    //  [80,144MB)  : Vt  1024x32768 bf16
    //  [144,208MB) : Anb 32768x1024 bf16   (fast path only)
    //  [208,212MB) : xb  2048x1024 bf16    (fast path only)
    if (ws_size < (size_t)144*1024*1024) return;
    const bool big = ws_size >= (size_t)212*1024*1024;
    u16* wW  = (u16*)ws;
    u16* Qa  = (u16*)(ws + (size_t) 8*1024*1024);
    u16* Om  = (u16*)(ws + (size_t)12*1024*1024);
    u16* Ka  = (u16*)(ws + (size_t)16*1024*1024);
    u16* Vt  = (u16*)(ws + (size_t)80*1024*1024);
    u16* Anb = (u16*)(ws + (size_t)144*1024*1024);
    u16* xb  = (u16*)(ws + (size_t)208*1024*1024);
    u16* wWq = wW, *wWk = wW + 1048576, *wWo = wW + 3*1048576;

    convert_all<<<dim3(4096), dim3(256), 0, stream>>>(
        Wq, Wk, Wv, Wo, nb, x, wW, Anb, xb, big ? 1 : 0);

    if (big) {
        // Q projection: 2048x1024, 16x8 tiles (128-tile kernel)
        gemm128<false, 0><<<dim3(128), dim3(256), 0, stream>>>(
            xb, 1024, wWq, 1024, Qa, nullptr, 2048, 1024, 0, 8);
        // fused K+V projection: 32768x2048, 128x8 256-tiles
        gemm256<3><<<dim3(1024), dim3(512), 0, stream>>>(
            Anb, 1024, wWk, 1024, Ka, Vt, 32768, 1024, 8);
    } else {
        gemm128<true, 0><<<dim3(128), dim3(256), 0, stream>>>(
            x, 1024, wWq, 1024, Qa, nullptr, 2048, 1024, 0, 8);
        gemm128<true, 3><<<dim3(4096), dim3(256), 0, stream>>>(
            nb, 1024, wWk, 1024, Ka, Vt, 32768, 1024, 0, 16);
    }

    attn_kernel<<<dim3(31, 16), dim3(256), 0, stream>>>(Qa, Ka, Vt, Om);
    last_kernel<<<dim3(256),    dim3(256), 0, stream>>>(Vt, Om);

    gemm128<false, 2><<<dim3(128), dim3(256), 0, stream>>>(
        Om, 1024, wWo, 1024, out, nullptr, 1985, 1024, 63, 8);
    copy_head<<<dim3(63), dim3(256), 0, stream>>>(x, out);
}